// Round 12
// baseline (393.069 us; speedup 1.0000x reference)
//
#include <hip/hip_runtime.h>

// RGAT: 2-layer, 2-relation GAT. N=20000, E=320000/rel, D=128, H=2.
// Round 12: aggs use no-max softmax (logits bounded; alpha = exp(e)*inv):
// stats phase deleted (staging computes exp + partial sums; one butterfly);
// aggout gathers over a unified rel0+rel1 edge list (row = src + rel*NN).
// Rest identical to round 11 (392 us).

#define NN 20000
#define NE 320000

typedef unsigned short bf16_t;
typedef __attribute__((ext_vector_type(8))) short short8;
typedef __attribute__((ext_vector_type(4))) float f32x4;

__device__ __forceinline__ float bf2f(bf16_t u) {
    return __uint_as_float(((unsigned)u) << 16);
}
__device__ __forceinline__ bf16_t f2bf(float f) {
    unsigned x = __float_as_uint(f);
    unsigned r = (x + 0x7fffu + ((x >> 16) & 1u)) >> 16;   // RNE
    return (bf16_t)r;
}
__device__ __forceinline__ float lrelu(float v) {
    return (v > 0.f) ? v : 0.2f * v;
}
__device__ __forceinline__ void load_x2(const void* x, int flag, int idx,
                                        float& v0, float& v1) {
    if (flag) {
        float2 f = ((const float2*)x)[idx];
        v0 = f.x; v1 = f.y;
    } else {
        unsigned pk = ((const unsigned*)x)[idx];
        v0 = bf2f((bf16_t)(pk & 0xffffu));
        v1 = bf2f((bf16_t)(pk >> 16));
    }
}

// ------------- convert 16 float tensors (weights) to bf16 + zero region -----
#define NTC 16
struct CzArgs {
    const void* src[NTC];
    bf16_t* dst[NTC];
    int n[NTC];
    int nblk[NTC + 1];
    int* zero_ptr;
    int zn;
    const unsigned* xsrc;
    int* flag_out;
};
__global__ void convzero_kernel(CzArgs a) {
    __shared__ int fl_s;
    int t = threadIdx.x;
    if (t < 64) {
        float mx = 0.f;
        for (int i = t; i < 256; i += 64) {
            float v = fabsf(bf2f((bf16_t)(a.xsrc[i] & 0xffffu)));
            v = (v <= 1e30f) ? v : 1e30f;
            mx = fmaxf(mx, v);
        }
        for (int off = 32; off > 0; off >>= 1) mx = fmaxf(mx, __shfl_xor(mx, off));
        if (t == 0) {
            int f = (mx > 1e6f) ? 1 : 0;
            fl_s = f;
            if (blockIdx.x == 0) *a.flag_out = f;
        }
    }
    __syncthreads();
    int flag = fl_s;
    int b = blockIdx.x;
    int ti = 0;
#pragma unroll 1
    for (; ti <= NTC; ++ti) {
        if (b < a.nblk[ti]) break;
        b -= a.nblk[ti];
    }
    int i = b * 256 + t;
    if (ti < NTC) {
        if (i < a.n[ti]) {
            if (flag) a.dst[ti][i] = f2bf(((const float*)a.src[ti])[i]);
            else      a.dst[ti][i] = ((const bf16_t*)a.src[ti])[i];
        }
    } else {
        if (i < a.zn) a.zero_ptr[i] = 0;
    }
}

// ---------------- prep: wal/war vectors, biases, frag repacks ----------------
struct PrepArgs {
    const bf16_t *W1[2], *W2[2];
    const bf16_t *al1[2], *ar1[2], *al2[2], *ar2[2];
    const bf16_t *b1[2], *b2[2];
    float *wal1, *war1;     // [2rel*2h*128]
    float *wal2, *war2;     // [2rel*2h*256]
    float *bc1, *bc2;       // [256], [128]
    bf16_t *Wc1f;           // combined layer-1 weight, frag order (K=512,M=256)
    bf16_t *Wzf;            // per-rel 0.5*W2 frag tables (K=256,M=256) x2
};
// bx: [0,4) wal1/war1 | [4,12) wal2/war2 | [12,14) bc | [14,78) Wc1f | [78,142) Wzf
__device__ __forceinline__ void prep_body(const PrepArgs& p, int bx, int tid) {
    if (bx < 4) {
        int t = bx * 256 + tid;
        int lr = t >> 9, rel = (t >> 8) & 1, h = (t >> 7) & 1, k = t & 127;
        const bf16_t* av = lr ? p.ar1[rel] : p.al1[rel];
        const bf16_t* W = p.W1[rel];
        float s = 0.f;
        for (int o = 0; o < 256; ++o)
            s += bf2f(W[k * 512 + h * 256 + o]) * bf2f(av[h * 256 + o]);
        (lr ? p.war1 : p.wal1)[(rel * 2 + h) * 128 + k] = s;
    } else if (bx < 12) {
        int t = (bx - 4) * 256 + tid;
        int lr = t >> 10, rel = (t >> 9) & 1, h = (t >> 8) & 1, k = t & 255;
        const bf16_t* av = lr ? p.ar2[rel] : p.al2[rel];
        const bf16_t* W = p.W2[rel];
        float s = 0.f;
        for (int o = 0; o < 128; ++o)
            s += bf2f(W[k * 256 + h * 128 + o]) * bf2f(av[h * 128 + o]);
        (lr ? p.war2 : p.wal2)[(rel * 2 + h) * 256 + k] = s;
    } else if (bx < 14) {
        int t = (bx - 12) * 256 + tid;
        if (t < 256) {
            p.bc1[t] = 0.5f * (bf2f(p.b1[0][t]) + bf2f(p.b1[0][256 + t]) +
                               bf2f(p.b1[1][t]) + bf2f(p.b1[1][256 + t]));
        } else if (t < 384) {
            int o = t - 256;
            p.bc2[o] = 0.5f * (bf2f(p.b2[0][o]) + bf2f(p.b2[0][128 + o]) +
                               bf2f(p.b2[1][o]) + bf2f(p.b2[1][128 + o]));
        }
    } else if (bx < 78) {               // Wc1f: K=512, M=256, KS=16
        int i = (bx - 14) * 256 + tid;
        int lane = i & 63;
        int t2 = i >> 6;
        int ct = t2 >> 4, ks = t2 & 15;
        int col = ct * 16 + (lane & 15);
        bf16_t* out = p.Wc1f + (size_t)i * 8;
#pragma unroll
        for (int j = 0; j < 8; ++j) {
            int r = ks * 32 + ((lane >> 4) << 3) + j;
            int rel = r >> 8, h = (r >> 7) & 1, kx = r & 127;
            out[j] = f2bf(0.5f * bf2f(p.W1[rel][kx * 512 + h * 256 + col]));
        }
    } else {                            // Wzf: per rel K=256, M=256, KS=8
        int b = bx - 78;
        int rel = b >> 5;
        int i = (b & 31) * 256 + tid;
        int lane = i & 63;
        int t2 = i >> 6;
        int ct = t2 >> 3, ks = t2 & 7;
        int col = ct * 16 + (lane & 15);
        bf16_t* out = p.Wzf + (size_t)rel * 65536 + (size_t)i * 8;
#pragma unroll
        for (int j = 0; j < 8; ++j) {
            int r = ks * 32 + ((lane >> 4) << 3) + j;
            out[j] = f2bf(0.5f * bf2f(p.W2[rel][r * 256 + col]));
        }
    }
}

// ---------------- CSR build ----------------
struct Csr2 {
    const int* src[2];
    const int* dst[2];
    int* cnt[2];
    int* offs[2];
    int* cursor[2];
    int* srcc[2];
};
struct PhArgs { PrepArgs p; Csr2 c; };
__global__ void prep_hist_kernel(PhArgs a) {
    int bx = blockIdx.x;
    if (bx < 142) {
        prep_body(a.p, bx, threadIdx.x);
    } else {
        int b = bx - 142;
        int rel = b / 1250;
        int i = (b - rel * 1250) * 256 + threadIdx.x;
        if (i < NE) atomicAdd(&a.c.cnt[rel][a.c.dst[rel][i]], 1);
    }
}

__global__ void scan2_kernel(Csr2 c, int n) {
    int rel = blockIdx.x;
    const int* cnt = c.cnt[rel];
    int* offs = c.offs[rel];
    int* cursor = c.cursor[rel];
    __shared__ int sums[256];
    int t = threadIdx.x;
    int chunk = (n + 255) >> 8;
    int lo = t * chunk;
    int hi = min(lo + chunk, n);
    int s = 0;
    for (int i = lo; i < hi; ++i) s += cnt[i];
    sums[t] = s;
    __syncthreads();
    if (t == 0) {
        int run = 0;
        for (int i = 0; i < 256; ++i) { int v = sums[i]; sums[i] = run; run += v; }
    }
    __syncthreads();
    int run = sums[t];
    for (int i = lo; i < hi; ++i) { int v = cnt[i]; offs[i] = run; cursor[i] = run; run += v; }
    if (t == 255) offs[n] = run;
}

// merged: elr1 (5000 blocks, dual-path x) + scatter (2x1250 blocks)
__global__ void scat_elr_kernel(Csr2 c, const void* __restrict__ x,
                                const int* __restrict__ flagp,
                                const float* __restrict__ wal1,
                                const float* __restrict__ war1,
                                float* __restrict__ el0, float* __restrict__ er0,
                                float* __restrict__ el1, float* __restrict__ er1) {
    __shared__ float wl[512], wr[512];
    int t = threadIdx.x;
    if (blockIdx.x < 5000) {
        wl[t] = wal1[t]; wl[t + 256] = wal1[t + 256];
        wr[t] = war1[t]; wr[t + 256] = war1[t + 256];
        __syncthreads();
        int fl = *flagp;
        int w = t >> 6, lane = t & 63;
        int node = blockIdx.x * 4 + w;
        float v0, v1;
        load_x2(x, fl, node * 64 + lane, v0, v1);
        float de[4], dr[4];
#pragma unroll
        for (int cch = 0; cch < 4; ++cch) {
            de[cch] = v0 * wl[cch * 128 + 2 * lane] + v1 * wl[cch * 128 + 2 * lane + 1];
            dr[cch] = v0 * wr[cch * 128 + 2 * lane] + v1 * wr[cch * 128 + 2 * lane + 1];
        }
#pragma unroll
        for (int off = 32; off > 0; off >>= 1) {
#pragma unroll
            for (int cch = 0; cch < 4; ++cch) {
                de[cch] += __shfl_xor(de[cch], off);
                dr[cch] += __shfl_xor(dr[cch], off);
            }
        }
        if (lane == 0) {
            el0[node * 2 + 0] = de[0]; el0[node * 2 + 1] = de[1];
            el1[node * 2 + 0] = de[2]; el1[node * 2 + 1] = de[3];
            er0[node * 2 + 0] = dr[0]; er0[node * 2 + 1] = dr[1];
            er1[node * 2 + 0] = dr[2]; er1[node * 2 + 1] = dr[3];
        }
    } else {
        int b = blockIdx.x - 5000;
        int rel = b / 1250;
        int i = (b - rel * 1250) * 256 + t;
        if (i < NE) {
            int p = atomicAdd(&c.cursor[rel][c.dst[rel][i]], 1);
            c.srcc[rel][p] = c.src[rel][i];
        }
    }
}

// ---------------- agg1: no-max softmax + gather x rows -> y1[N,512] ---------
__global__ void agg1_kernel(
    const int* __restrict__ offs0, const int* __restrict__ srcc0,
    const float* __restrict__ el0, const float* __restrict__ er0,
    const int* __restrict__ offs1, const int* __restrict__ srcc1,
    const float* __restrict__ el1, const float* __restrict__ er1,
    const void* __restrict__ x, const int* __restrict__ flagp,
    bf16_t* __restrict__ y1) {
    constexpr int CAP = 64;
    __shared__ float sh[4][512];
    __shared__ int   ss[2 * CAP];
    __shared__ float se[4 * CAP];
    __shared__ float red[4][4];
    int d = blockIdx.x;
    int t = threadIdx.x;
    int w = t >> 6, lane = t & 63;
    int beg0 = offs0[d], deg0 = offs0[d + 1] - beg0;
    int beg1 = offs1[d], deg1 = offs1[d + 1] - beg1;
    int c0 = min(deg0, CAP), c1 = min(deg1, CAP);
    float er00 = er0[d * 2], er01 = er0[d * 2 + 1];
    float er10 = er1[d * 2], er11 = er1[d * 2 + 1];

    // ---- stage p = exp(lrelu(e)) + per-thread partial sums ----
    float ps0 = 0.f, ps1 = 0.f, ps2 = 0.f, ps3 = 0.f;
    for (int j = t; j < c0; j += 256) {
        int s = srcc0[beg0 + j];
        ss[j] = s;
        float2 ev = ((const float2*)el0)[s];
        float p0 = __expf(lrelu(ev.x + er00));
        float p1 = __expf(lrelu(ev.y + er01));
        se[2 * j] = p0; se[2 * j + 1] = p1;
        ps0 += p0; ps1 += p1;
    }
    for (int j = t; j < c1; j += 256) {
        int s = srcc1[beg1 + j];
        ss[CAP + j] = s;
        float2 ev = ((const float2*)el1)[s];
        float p0 = __expf(lrelu(ev.x + er10));
        float p1 = __expf(lrelu(ev.y + er11));
        se[2 * CAP + 2 * j] = p0; se[2 * CAP + 2 * j + 1] = p1;
        ps2 += p0; ps3 += p1;
    }
    for (int j = CAP + t; j < deg0; j += 256) {      // overflow sums (cold)
        int s = srcc0[beg0 + j];
        float2 ev = ((const float2*)el0)[s];
        ps0 += __expf(lrelu(ev.x + er00));
        ps1 += __expf(lrelu(ev.y + er01));
    }
    for (int j = CAP + t; j < deg1; j += 256) {
        int s = srcc1[beg1 + j];
        float2 ev = ((const float2*)el1)[s];
        ps2 += __expf(lrelu(ev.x + er10));
        ps3 += __expf(lrelu(ev.y + er11));
    }
#pragma unroll
    for (int off = 32; off > 0; off >>= 1) {
        ps0 += __shfl_xor(ps0, off);
        ps1 += __shfl_xor(ps1, off);
        ps2 += __shfl_xor(ps2, off);
        ps3 += __shfl_xor(ps3, off);
    }
    if (lane == 0) {
        red[w][0] = ps0; red[w][1] = ps1; red[w][2] = ps2; red[w][3] = ps3;
    }
    __syncthreads();
    float inv0 = 1.f / fmaxf(red[0][0] + red[1][0] + red[2][0] + red[3][0], 1e-9f);
    float inv1 = 1.f / fmaxf(red[0][1] + red[1][1] + red[2][1] + red[3][1], 1e-9f);
    float inv2 = 1.f / fmaxf(red[0][2] + red[1][2] + red[2][2] + red[3][2], 1e-9f);
    float inv3 = 1.f / fmaxf(red[0][3] + red[1][3] + red[2][3] + red[3][3], 1e-9f);
    for (int j = t; j < c0; j += 256) {
        se[2 * j] *= inv0; se[2 * j + 1] *= inv1;
    }
    for (int j = t; j < c1; j += 256) {
        se[2 * CAP + 2 * j] *= inv2; se[2 * CAP + 2 * j + 1] *= inv3;
    }
    __syncthreads();

    int fl = *flagp;
    float a00 = 0.f, a01 = 0.f, a10 = 0.f, a11 = 0.f;
    float b00 = 0.f, b01 = 0.f, b10 = 0.f, b11 = 0.f;
    {
        auto get0 = [&](int jj, int& s, float& p0, float& p1) {
            if (jj < CAP) {
                s = ss[jj];
                p0 = se[2 * jj];
                p1 = se[2 * jj + 1];
            } else {
                s = srcc0[beg0 + jj];
                float2 ev = ((const float2*)el0)[s];
                p0 = __expf(lrelu(ev.x + er00)) * inv0;
                p1 = __expf(lrelu(ev.y + er01)) * inv1;
            }
        };
        int jj = w;
        for (; jj + 12 < deg0; jj += 16) {
            int sA, sB, sC, sD;
            float pA0, pA1, pB0, pB1, pC0, pC1, pD0, pD1;
            get0(jj, sA, pA0, pA1);
            get0(jj + 4, sB, pB0, pB1);
            get0(jj + 8, sC, pC0, pC1);
            get0(jj + 12, sD, pD0, pD1);
            float vA0, vA1, vB0, vB1, vC0, vC1, vD0, vD1;
            load_x2(x, fl, sA * 64 + lane, vA0, vA1);
            load_x2(x, fl, sB * 64 + lane, vB0, vB1);
            load_x2(x, fl, sC * 64 + lane, vC0, vC1);
            load_x2(x, fl, sD * 64 + lane, vD0, vD1);
            a00 += pA0 * vA0 + pB0 * vB0 + pC0 * vC0 + pD0 * vD0;
            a01 += pA0 * vA1 + pB0 * vB1 + pC0 * vC1 + pD0 * vD1;
            a10 += pA1 * vA0 + pB1 * vB0 + pC1 * vC0 + pD1 * vD0;
            a11 += pA1 * vA1 + pB1 * vB1 + pC1 * vC1 + pD1 * vD1;
        }
        for (; jj < deg0; jj += 4) {
            int sA;
            float pA0, pA1;
            get0(jj, sA, pA0, pA1);
            float vA0, vA1;
            load_x2(x, fl, sA * 64 + lane, vA0, vA1);
            a00 += pA0 * vA0; a01 += pA0 * vA1;
            a10 += pA1 * vA0; a11 += pA1 * vA1;
        }
    }
    {
        auto get1 = [&](int jj, int& s, float& p0, float& p1) {
            if (jj < CAP) {
                s = ss[CAP + jj];
                p0 = se[2 * CAP + 2 * jj];
                p1 = se[2 * CAP + 2 * jj + 1];
            } else {
                s = srcc1[beg1 + jj];
                float2 ev = ((const float2*)el1)[s];
                p0 = __expf(lrelu(ev.x + er10)) * inv2;
                p1 = __expf(lrelu(ev.y + er11)) * inv3;
            }
        };
        int jj = w;
        for (; jj + 12 < deg1; jj += 16) {
            int sA, sB, sC, sD;
            float pA0, pA1, pB0, pB1, pC0, pC1, pD0, pD1;
            get1(jj, sA, pA0, pA1);
            get1(jj + 4, sB, pB0, pB1);
            get1(jj + 8, sC, pC0, pC1);
            get1(jj + 12, sD, pD0, pD1);
            float vA0, vA1, vB0, vB1, vC0, vC1, vD0, vD1;
            load_x2(x, fl, sA * 64 + lane, vA0, vA1);
            load_x2(x, fl, sB * 64 + lane, vB0, vB1);
            load_x2(x, fl, sC * 64 + lane, vC0, vC1);
            load_x2(x, fl, sD * 64 + lane, vD0, vD1);
            b00 += pA0 * vA0 + pB0 * vB0 + pC0 * vC0 + pD0 * vD0;
            b01 += pA0 * vA1 + pB0 * vB1 + pC0 * vC1 + pD0 * vD1;
            b10 += pA1 * vA0 + pB1 * vB0 + pC1 * vC0 + pD1 * vD0;
            b11 += pA1 * vA1 + pB1 * vB1 + pC1 * vC1 + pD1 * vD1;
        }
        for (; jj < deg1; jj += 4) {
            int sA;
            float pA0, pA1;
            get1(jj, sA, pA0, pA1);
            float vA0, vA1;
            load_x2(x, fl, sA * 64 + lane, vA0, vA1);
            b00 += pA0 * vA0; b01 += pA0 * vA1;
            b10 += pA1 * vA0; b11 += pA1 * vA1;
        }
    }
    sh[w][0 + 2 * lane] = a00;       sh[w][0 + 2 * lane + 1] = a01;
    sh[w][128 + 2 * lane] = a10;     sh[w][128 + 2 * lane + 1] = a11;
    sh[w][256 + 2 * lane] = b00;     sh[w][256 + 2 * lane + 1] = b01;
    sh[w][384 + 2 * lane] = b10;     sh[w][384 + 2 * lane + 1] = b11;
    __syncthreads();
#pragma unroll
    for (int rep = 0; rep < 2; ++rep) {
        int o = t + rep * 256;
        float v = sh[0][o] + sh[1][o] + sh[2][o] + sh[3][o];
        y1[(size_t)d * 512 + o] = f2bf(v);
    }
}

// -------- gemm1: h1 = relu(y1 @ Wc1 + bc1); 8 col-frags/wave; el2/er2 -------
__global__ void gemm1_kernel(const bf16_t* __restrict__ A, const bf16_t* __restrict__ Wf,
                             const float* __restrict__ bc1, bf16_t* __restrict__ h1,
                             const float* __restrict__ wal2, const float* __restrict__ war2,
                             float* __restrict__ el2_0, float* __restrict__ er2_0,
                             float* __restrict__ el2_1, float* __restrict__ er2_1,
                             int n) {
    constexpr int K = 512, M = 256, KS = 16, NF = 8;
    int w = threadIdx.x >> 6, lane = threadIdx.x & 63;
    int q = lane >> 4, m16 = lane & 15;
    int rf = blockIdx.y * 64 + w * 16;
    if (rf >= n) return;
    f32x4 acc[NF] = {};
    const bf16_t* Arow = A + (size_t)(rf + m16) * K + q * 8;
    for (int ks = 0; ks < KS; ++ks) {
        short8 af = *(const short8*)(Arow + ks * 32);
#pragma unroll
        for (int f = 0; f < NF; ++f) {
            int ct = blockIdx.x * NF + f;
            short8 bfr = *(const short8*)(Wf + ((size_t)(ct * KS + ks) * 64 + lane) * 8);
            acc[f] = __builtin_amdgcn_mfma_f32_16x16x32_bf16(af, bfr, acc[f], 0, 0, 0);
        }
    }
    int col0 = blockIdx.x * (NF * 16);
    float del[2][2][4] = {};
    float der[2][2][4] = {};
#pragma unroll
    for (int f = 0; f < NF; ++f) {
        int col = col0 + f * 16 + m16;
        float bcv = bc1[col];
        float wle[2][2], wre[2][2];
#pragma unroll
        for (int rel = 0; rel < 2; ++rel)
#pragma unroll
            for (int h = 0; h < 2; ++h) {
                wle[rel][h] = wal2[(rel * 2 + h) * 256 + col];
                wre[rel][h] = war2[(rel * 2 + h) * 256 + col];
            }
#pragma unroll
        for (int r = 0; r < 4; ++r) {
            int row = rf + q * 4 + r;
            float v = fmaxf(acc[f][r] + bcv, 0.f);
            bf16_t hb = f2bf(v);
            h1[(size_t)row * M + col] = hb;
            float vb = bf2f(hb);
#pragma unroll
            for (int rel = 0; rel < 2; ++rel)
#pragma unroll
                for (int h = 0; h < 2; ++h) {
                    del[rel][h][r] += vb * wle[rel][h];
                    der[rel][h][r] += vb * wre[rel][h];
                }
        }
    }
#pragma unroll
    for (int off = 1; off < 16; off <<= 1) {
#pragma unroll
        for (int rel = 0; rel < 2; ++rel)
#pragma unroll
            for (int h = 0; h < 2; ++h)
#pragma unroll
                for (int r = 0; r < 4; ++r) {
                    del[rel][h][r] += __shfl_xor(del[rel][h][r], off);
                    der[rel][h][r] += __shfl_xor(der[rel][h][r], off);
                }
    }
    if (m16 == 0) {
#pragma unroll
        for (int r = 0; r < 4; ++r) {
            int row = rf + q * 4 + r;
            atomicAdd(&el2_0[row * 2 + 0], del[0][0][r]);
            atomicAdd(&el2_0[row * 2 + 1], del[0][1][r]);
            atomicAdd(&el2_1[row * 2 + 0], del[1][0][r]);
            atomicAdd(&el2_1[row * 2 + 1], del[1][1][r]);
            atomicAdd(&er2_0[row * 2 + 0], der[0][0][r]);
            atomicAdd(&er2_0[row * 2 + 1], der[0][1][r]);
            atomicAdd(&er2_1[row * 2 + 0], der[1][0][r]);
            atomicAdd(&er2_1[row * 2 + 1], der[1][1][r]);
        }
    }
}

// -------- gemmZ: z_rel = h1 @ (0.5*W2_rel); 8 col-frags/wave, grid.z=2 ------
__global__ void gemmz_kernel(const bf16_t* __restrict__ A, const bf16_t* __restrict__ Wzf,
                             bf16_t* __restrict__ z, int n) {
    constexpr int K = 256, M = 256, KS = 8, NF = 8;
    int rel = blockIdx.z;
    const bf16_t* Wf = Wzf + (size_t)rel * 65536;
    bf16_t* C = z + (size_t)rel * NN * 256;
    int w = threadIdx.x >> 6, lane = threadIdx.x & 63;
    int q = lane >> 4, m16 = lane & 15;
    int rf = blockIdx.y * 64 + w * 16;
    if (rf >= n) return;
    f32x4 acc[NF] = {};
    const bf16_t* Arow = A + (size_t)(rf + m16) * K + q * 8;
    for (int ks = 0; ks < KS; ++ks) {
        short8 af = *(const short8*)(Arow + ks * 32);
#pragma unroll
        for (int f = 0; f < NF; ++f) {
            int ct = blockIdx.x * NF + f;
            short8 bfr = *(const short8*)(Wf + ((size_t)(ct * KS + ks) * 64 + lane) * 8);
            acc[f] = __builtin_amdgcn_mfma_f32_16x16x32_bf16(af, bfr, acc[f], 0, 0, 0);
        }
    }
    int col0 = blockIdx.x * (NF * 16);
#pragma unroll
    for (int f = 0; f < NF; ++f) {
#pragma unroll
        for (int r = 0; r < 4; ++r) {
            int row = rf + q * 4 + r;
            C[(size_t)row * M + col0 + f * 16 + m16] = f2bf(acc[f][r]);
        }
    }
}

// -------- aggout: no-max softmax + unified rel0+rel1 gather -> out[N,128] ---
// Staged row index = src + rel*NN, so one gather loop covers both relations.
__global__ void aggout_kernel(
    const int* __restrict__ offs0, const int* __restrict__ srcc0,
    const float* __restrict__ el0, const float* __restrict__ er0,
    const int* __restrict__ offs1, const int* __restrict__ srcc1,
    const float* __restrict__ el1, const float* __restrict__ er1,
    const bf16_t* __restrict__ z, const float* __restrict__ bc2,
    void* __restrict__ out, const int* __restrict__ flagp) {
    constexpr int CAP = 64;
    __shared__ float sh[4][256];
    __shared__ int   ss[2 * CAP];
    __shared__ float se[4 * CAP];
    __shared__ float red[4][4];
    int d = blockIdx.x;
    int t = threadIdx.x;
    int w = t >> 6, lane = t & 63;
    int beg0 = offs0[d], deg0 = offs0[d + 1] - beg0;
    int beg1 = offs1[d], deg1 = offs1[d + 1] - beg1;
    int c0 = min(deg0, CAP), c1 = min(deg1, CAP);
    float er00 = er0[d * 2], er01 = er0[d * 2 + 1];
    float er10 = er1[d * 2], er11 = er1[d * 2 + 1];

    // ---- stage p = exp(lrelu(e)) at unified slot (rel1 after rel0) ----
    float ps0 = 0.f, ps1 = 0.f, ps2 = 0.f, ps3 = 0.f;
    for (int j = t; j < c0; j += 256) {
        int s = srcc0[beg0 + j];
        ss[j] = s;                                  // row in z (rel 0)
        float2 ev = ((const float2*)el0)[s];
        float p0 = __expf(lrelu(ev.x + er00));
        float p1 = __expf(lrelu(ev.y + er01));
        se[2 * j] = p0; se[2 * j + 1] = p1;
        ps0 += p0; ps1 += p1;
    }
    for (int j = t; j < c1; j += 256) {
        int s = srcc1[beg1 + j];
        ss[c0 + j] = s + NN;                        // row in z (rel 1)
        float2 ev = ((const float2*)el1)[s];
        float p0 = __expf(lrelu(ev.x + er10));
        float p1 = __expf(lrelu(ev.y + er11));
        se[2 * (c0 + j)] = p0; se[2 * (c0 + j) + 1] = p1;
        ps2 += p0; ps3 += p1;
    }
    for (int j = CAP + t; j < deg0; j += 256) {     // overflow sums (cold)
        int s = srcc0[beg0 + j];
        float2 ev = ((const float2*)el0)[s];
        ps0 += __expf(lrelu(ev.x + er00));
        ps1 += __expf(lrelu(ev.y + er01));
    }
    for (int j = CAP + t; j < deg1; j += 256) {
        int s = srcc1[beg1 + j];
        float2 ev = ((const float2*)el1)[s];
        ps2 += __expf(lrelu(ev.x + er10));
        ps3 += __expf(lrelu(ev.y + er11));
    }
#pragma unroll
    for (int off = 32; off > 0; off >>= 1) {
        ps0 += __shfl_xor(ps0, off);
        ps1 += __shfl_xor(ps1, off);
        ps2 += __shfl_xor(ps2, off);
        ps3 += __shfl_xor(ps3, off);
    }
    if (lane == 0) {
        red[w][0] = ps0; red[w][1] = ps1; red[w][2] = ps2; red[w][3] = ps3;
    }
    __syncthreads();
    float inv0 = 1.f / fmaxf(red[0][0] + red[1][0] + red[2][0] + red[3][0], 1e-9f);
    float inv1 = 1.f / fmaxf(red[0][1] + red[1][1] + red[2][1] + red[3][1], 1e-9f);
    float inv2 = 1.f / fmaxf(red[0][2] + red[1][2] + red[2][2] + red[3][2], 1e-9f);
    float inv3 = 1.f / fmaxf(red[0][3] + red[1][3] + red[2][3] + red[3][3], 1e-9f);
    for (int j = t; j < c0; j += 256) {
        se[2 * j] *= inv0; se[2 * j + 1] *= inv1;
    }
    for (int j = t; j < c1; j += 256) {
        se[2 * (c0 + j)] *= inv2; se[2 * (c0 + j) + 1] *= inv3;
    }
    __syncthreads();

    // ---- unified gather over ctot staged edges ----
    int ctot = c0 + c1;
    int head = lane >> 5;                 // lanes 0-31 head 0, 32-63 head 1
    float acc[4] = {};
    const uint2* zp = (const uint2*)z;
    int jj = w;
    for (; jj + 12 < ctot; jj += 16) {
        int sA = ss[jj], sB = ss[jj + 4], sC = ss[jj + 8], sD = ss[jj + 12];
        float aA = se[2 * jj + head];
        float aB = se[2 * (jj + 4) + head];
        float aC = se[2 * (jj + 8) + head];
        float aD = se[2 * (jj + 12) + head];
        uint2 pkA = zp[(size_t)sA * 64 + lane];
        uint2 pkB = zp[(size_t)sB * 64 + lane];
        uint2 pkC = zp[(size_t)sC * 64 + lane];
        uint2 pkD = zp[(size_t)sD * 64 + lane];
        acc[0] += aA * bf2f((bf16_t)(pkA.x & 0xffffu)) + aB * bf2f((bf16_t)(pkB.x & 0xffffu))
                + aC * bf2f((bf16_t)(pkC.x & 0xffffu)) + aD * bf2f((bf16_t)(pkD.x & 0xffffu));
        acc[1] += aA * bf2f((bf16_t)(pkA.x >> 16)) + aB * bf2f((bf16_t)(pkB.x >> 16))
                + aC * bf2f((bf16_t)(pkC.x >> 16)) + aD * bf2f((bf16_t)(pkD.x >> 16));
        acc[2] += aA * bf2f((bf16_t)(pkA.y & 0xffffu)) + aB * bf2f((bf16_t)(pkB.y & 0xffffu))
                + aC * bf2f((bf16_t)(pkC.y & 0xffffu)) + aD * bf2f((bf16_t)(pkD.y & 0xffffu));
        acc[3] += aA * bf2f((bf16_t)(pkA.y >> 16)) + aB * bf2f((bf16_t)(pkB.y >> 16))
                + aC * bf2f((bf16_t)(pkC.y >> 16)) + aD * bf2f((bf16_t)(pkD.y >> 16));
    }
    for (; jj < ctot; jj += 4) {
        int sA = ss[jj];
        float aA = se[2 * jj + head];
        uint2 pk = zp[(size_t)sA * 64 + lane];
        acc[0] += aA * bf2f((bf16_t)(pk.x & 0xffffu));
        acc[1] += aA * bf2f((bf16_t)(pk.x >> 16));
        acc[2] += aA * bf2f((bf16_t)(pk.y & 0xffffu));
        acc[3] += aA * bf2f((bf16_t)(pk.y >> 16));
    }
    // overflow gather (cold)
    for (int j2 = CAP + w; j2 < deg0; j2 += 4) {
        int s = srcc0[beg0 + j2];
        float2 ev = ((const float2*)el0)[s];
        float a = __expf(lrelu((head ? ev.y : ev.x) + (head ? er01 : er00)))
                * (head ? inv1 : inv0);
        uint2 pk = zp[(size_t)s * 64 + lane];
        acc[0] += a * bf2f((bf16_t)(pk.x & 0xffffu));
        acc[1] += a * bf2f((bf16_t)(pk.x >> 16));
        acc[2] += a * bf2f((bf16_t)(pk.y & 0xffffu));
        acc[3] += a * bf2f((bf16_t)(pk.y >> 16));
    }
    for (int j2 = CAP + w; j2 < deg1; j2 += 4) {
        int s = srcc1[beg1 + j2];
        float2 ev = ((const float2*)el1)[s];
        float a = __expf(lrelu((head ? ev.y : ev.x) + (head ? er11 : er10)))
                * (head ? inv3 : inv2);
        uint2 pk = zp[(size_t)(s + NN) * 64 + lane];
        acc[0] += a * bf2f((bf16_t)(pk.x & 0xffffu));
        acc[1] += a * bf2f((bf16_t)(pk.x >> 16));
        acc[2] += a * bf2f((bf16_t)(pk.y & 0xffffu));
        acc[3] += a * bf2f((bf16_t)(pk.y >> 16));
    }
#pragma unroll
    for (int k = 0; k < 4; ++k) sh[w][lane * 4 + k] = acc[k];   // idx = h*128+o
    __syncthreads();
    if (t < 128) {
        float v = bc2[t];
#pragma unroll
        for (int ww = 0; ww < 4; ++ww) v += sh[ww][t] + sh[ww][128 + t];
        if (*flagp) ((float*)out)[(size_t)d * 128 + t] = v;
        else        ((bf16_t*)out)[(size_t)d * 128 + t] = f2bf(v);
    }
}

extern "C" void kernel_launch(void* const* d_in, const int* in_sizes, int n_in,
                              void* d_out, int out_size, void* d_ws, size_t ws_size,
                              hipStream_t stream) {
    (void)in_sizes; (void)n_in; (void)out_size; (void)ws_size;
    const void* x0 = d_in[0];
    const int* src0 = (const int*)d_in[1];
    const int* dst0 = (const int*)d_in[2];
    const int* src1 = (const int*)d_in[3];
    const int* dst1 = (const int*)d_in[4];

    char* ws = (char*)d_ws;
    size_t off = 0;
    auto alloc = [&](size_t bytes) -> void* {
        void* p = ws + off;
        off = (off + bytes + 255) & ~(size_t)255;
        return p;
    };
    int* flag = (int*)alloc(4);
    static const int tn[NTC] = {128 * 512, 512, 512, 512,
                                128 * 512, 512, 512, 512,
                                256 * 256, 256, 256, 256,
                                256 * 256, 256, 256, 256};
    bf16_t* tb[NTC];
    for (int i = 0; i < NTC; ++i) tb[i] = (bf16_t*)alloc((size_t)tn[i] * 2);

    bf16_t* Wc1f = (bf16_t*)alloc((size_t)512 * 256 * 2);
    bf16_t* Wzf  = (bf16_t*)alloc((size_t)2 * 65536 * 2);
    float* wal1 = (float*)alloc(512 * 4);
    float* war1 = (float*)alloc(512 * 4);
    float* wal2 = (float*)alloc(1024 * 4);
    float* war2 = (float*)alloc(1024 * 4);
    float* bc1  = (float*)alloc(256 * 4);
    float* bc2  = (float*)alloc(128 * 4);

    char* zbeg = ws + off;
    int* cnt0 = (int*)alloc(NN * 4);
    int* cnt1 = (int*)alloc(NN * 4);
    float* el2_0 = (float*)alloc(NN * 2 * 4);
    float* er2_0 = (float*)alloc(NN * 2 * 4);
    float* el2_1 = (float*)alloc(NN * 2 * 4);
    float* er2_1 = (float*)alloc(NN * 2 * 4);
    char* zend = ws + off;
    int zcount = (int)((zend - zbeg) >> 2);

    int* offs0 = (int*)alloc((NN + 1) * 4);
    int* offs1 = (int*)alloc((NN + 1) * 4);
    int* cur0  = (int*)alloc(NN * 4);
    int* cur1  = (int*)alloc(NN * 4);
    int* srcc0 = (int*)alloc(NE * 4);
    int* srcc1 = (int*)alloc(NE * 4);
    float* el1_0 = (float*)alloc(NN * 2 * 4);
    float* er1_0 = (float*)alloc(NN * 2 * 4);
    float* el1_1 = (float*)alloc(NN * 2 * 4);
    float* er1_1 = (float*)alloc(NN * 2 * 4);
    bf16_t* h1 = (bf16_t*)alloc((size_t)NN * 256 * 2);
    bf16_t* Y  = (bf16_t*)alloc((size_t)NN * 1024 * 2);  // y1 [N,512]; later z [2][N,256]
    bf16_t* y1 = Y;
    bf16_t* z  = Y;   // safe: gemmZ writes z after gemm1 finished reading y1

    // ---- 1. convert weights + zero + inline dtype detect ----
    CzArgs cz;
    static const int din_idx[NTC] = {5, 6, 7, 8, 9, 10, 11, 12,
                                     13, 14, 15, 16, 17, 18, 19, 20};
    int total_blocks = 0;
    for (int i = 0; i < NTC; ++i) {
        cz.src[i] = d_in[din_idx[i]];
        cz.dst[i] = tb[i];
        cz.n[i] = tn[i];
        cz.nblk[i] = (tn[i] + 255) / 256;
        total_blocks += cz.nblk[i];
    }
    cz.zero_ptr = (int*)zbeg;
    cz.zn = zcount;
    cz.nblk[NTC] = (zcount + 255) / 256;
    total_blocks += cz.nblk[NTC];
    cz.xsrc = (const unsigned*)x0;
    cz.flag_out = flag;
    convzero_kernel<<<total_blocks, 256, 0, stream>>>(cz);

    // ---- 2. prep + hist ----
    PhArgs ph;
    ph.p.W1[0] = tb[0];  ph.p.W1[1] = tb[4];
    ph.p.W2[0] = tb[8];  ph.p.W2[1] = tb[12];
    ph.p.al1[0] = tb[1]; ph.p.ar1[0] = tb[2];
    ph.p.al1[1] = tb[5]; ph.p.ar1[1] = tb[6];
    ph.p.al2[0] = tb[9]; ph.p.ar2[0] = tb[10];
    ph.p.al2[1] = tb[13]; ph.p.ar2[1] = tb[14];
    ph.p.b1[0] = tb[3];  ph.p.b1[1] = tb[7];
    ph.p.b2[0] = tb[11]; ph.p.b2[1] = tb[15];
    ph.p.wal1 = wal1; ph.p.war1 = war1;
    ph.p.wal2 = wal2; ph.p.war2 = war2;
    ph.p.bc1 = bc1; ph.p.bc2 = bc2;
    ph.p.Wc1f = Wc1f; ph.p.Wzf = Wzf;
    ph.c.src[0] = src0; ph.c.src[1] = src1;
    ph.c.dst[0] = dst0; ph.c.dst[1] = dst1;
    ph.c.cnt[0] = cnt0; ph.c.cnt[1] = cnt1;
    ph.c.offs[0] = offs0; ph.c.offs[1] = offs1;
    ph.c.cursor[0] = cur0; ph.c.cursor[1] = cur1;
    ph.c.srcc[0] = srcc0; ph.c.srcc[1] = srcc1;
    prep_hist_kernel<<<142 + 2500, 256, 0, stream>>>(ph);

    // ---- 3. scan ----
    scan2_kernel<<<2, 256, 0, stream>>>(ph.c, NN);

    // ---- 4. scatter + elr1 (dual-path x) ----
    scat_elr_kernel<<<5000 + 2500, 256, 0, stream>>>(
        ph.c, x0, flag, wal1, war1, el1_0, er1_0, el1_1, er1_1);

    // ---- 5. agg1: gather x rows -> y1[N,512] ----
    agg1_kernel<<<NN, 256, 0, stream>>>(offs0, srcc0, el1_0, er1_0,
                                        offs1, srcc1, el1_1, er1_1, x0, flag, y1);

    // ---- 6. gemm1 -> h1, el2/er2 ----
    gemm1_kernel<<<dim3(2, 313), 256, 0, stream>>>(
        y1, Wc1f, bc1, h1, wal2, war2, el2_0, er2_0, el2_1, er2_1, NN);

    // ---- 7. gemmZ: z_rel = h1 @ (0.5*W2_rel) ----
    gemmz_kernel<<<dim3(2, 313, 2), 256, 0, stream>>>(h1, Wzf, z, NN);

    // ---- 8. aggout: gather z rows -> d_out ----
    aggout_kernel<<<NN, 256, 0, stream>>>(offs0, srcc0, el2_0, er2_0,
                                          offs1, srcc1, el2_1, er2_1,
                                          z, bc2, d_out, flag);
}